// Round 2
// baseline (289.218 us; speedup 1.0000x reference)
//
#include <hip/hip_runtime.h>

// Problem constants
#define LSEQ 1024
#define DMODEL 1024
#define NHEADS 16
#define FDIM 16
#define HDIM 64
#define DFEAT 273          // 1 + 16 + 256
#define CHUNK 64
#define NCHUNK 16
#define KVS 68             // padded row stride for kvc inner dim (65 used, 68 for 16B align)

__device__ __forceinline__ float bf2f(unsigned short u) {
    unsigned int x = ((unsigned int)u) << 16;
    return __builtin_bit_cast(float, x);
}
__device__ __forceinline__ unsigned short f2bf(float f) {
    unsigned int x = __builtin_bit_cast(unsigned int, f);
    unsigned int r = (x + 0x7fffu + ((x >> 16) & 1u)) >> 16;
    return (unsigned short)r;
}

#define C2F 0.17677669529663687f   // 1/(4*sqrt(2))

// ws float-index layout (all fp32):
//  hidF 0        (1048576)
//  WqF  1048576  (262144)
//  WkF  1310720  (262144)
//  WvF  1572864  (1048576)
//  WoF  2621440  (1048576)
//  qb   3670016  (262144)
//  kb   3932160  (262144)
//  vb   4194304  (1048576)
//  yb   5242880  (1048576)
//  kvc  6291456  (16*16*273*68 = 4752384)
//  flag 11043840 (1 int: 1 = inputs are fp32, 0 = bf16)
#define OFF_HID 0
#define OFF_WQ  1048576
#define OFF_WK  1310720
#define OFF_WV  1572864
#define OFF_WO  2621440
#define OFF_QB  3670016
#define OFF_KB  3932160
#define OFF_VB  4194304
#define OFF_YB  5242880
#define OFF_KVC 6291456
#define OFF_FLAG 11043840
#define NCONV 3670016      // total fp32 elements to convert (hid+Wq+Wk+Wv+Wo)

// ---------------------------------------------------------------------------
// Kernel 0: dtype detector. Examines exponent fields of the first 2048
// ushorts of Wq. bf16 data ~N(0,1/32): exponents cluster in ~[100,130].
// fp32 data read as ushorts: every other ushort is random mantissa bits ->
// uniform exponents -> ~75% "insane". flag=1 means fp32.
// ---------------------------------------------------------------------------
__global__ void detect_dtype(const unsigned short* __restrict__ wq, int* __restrict__ flag) {
    __shared__ int cnt;
    if (threadIdx.x == 0) cnt = 0;
    __syncthreads();
    int bad = 0;
    for (int i = threadIdx.x; i < 2048; i += 256) {
        int e = (wq[i] >> 7) & 0xFF;
        if (e >= 143 || (e > 0 && e <= 80)) bad++;
    }
    atomicAdd(&cnt, bad);
    __syncthreads();
    if (threadIdx.x == 0) *flag = (cnt > 256) ? 1 : 0;
}

// ---------------------------------------------------------------------------
// Kernel 0b: convert all five inputs to fp32, contiguous in ws.
// 4 elements per thread; grid = NCONV/4/256 = 3584 blocks exactly.
// ---------------------------------------------------------------------------
__global__ __launch_bounds__(256) void convert_inputs(
    const void* __restrict__ s0, const void* __restrict__ s1,
    const void* __restrict__ s2, const void* __restrict__ s3,
    const void* __restrict__ s4, float* __restrict__ ws,
    const int* __restrict__ flagp) {
    int fp32 = *flagp;
    size_t e = ((size_t)blockIdx.x * 256 + threadIdx.x) * 4;
    if (e >= NCONV) return;
    const void* src; size_t off;
    if (e < OFF_WQ)      { src = s0; off = e; }
    else if (e < OFF_WK) { src = s1; off = e - OFF_WQ; }
    else if (e < OFF_WV) { src = s2; off = e - OFF_WK; }
    else if (e < OFF_WO) { src = s3; off = e - OFF_WV; }
    else                 { src = s4; off = e - OFF_WO; }
    float4 v;
    if (fp32) {
        v = *(const float4*)((const float*)src + off);
    } else {
        ushort4 u = *(const ushort4*)((const unsigned short*)src + off);
        v = make_float4(bf2f(u.x), bf2f(u.y), bf2f(u.z), bf2f(u.w));
    }
    *(float4*)(ws + e) = v;
}

// ---------------------------------------------------------------------------
// Kernel 1: fused QKV projection (all fp32 now). C = A @ W^T.
// 64x64 output tile per block, 256 thr, 4x4 per thread.
// grid.x: 0..3 -> q cols, 4..7 -> k cols, 8..23 -> v cols. grid.y = row tile.
// ---------------------------------------------------------------------------
__global__ __launch_bounds__(256) void qkv_proj(
    const float* __restrict__ hid,
    const float* __restrict__ Wq,
    const float* __restrict__ Wk,
    const float* __restrict__ Wv,
    float* __restrict__ qb, float* __restrict__ kb, float* __restrict__ vb) {
    int nb = blockIdx.x, mb = blockIdx.y;
    const float* B;
    float* Cout; int ldc, col0;
    if (nb < 4)      { B = Wq + (size_t)nb * 64 * DMODEL;       Cout = qb; ldc = 256;  col0 = nb * 64; }
    else if (nb < 8) { B = Wk + (size_t)(nb - 4) * 64 * DMODEL; Cout = kb; ldc = 256;  col0 = (nb - 4) * 64; }
    else             { B = Wv + (size_t)(nb - 8) * 64 * DMODEL; Cout = vb; ldc = 1024; col0 = (nb - 8) * 64; }
    const float* A = hid + (size_t)mb * 64 * DMODEL;

    __shared__ __align__(16) float As[16][64];
    __shared__ __align__(16) float Bs[16][64];
    int t = threadIdx.x;
    int lr = t >> 2;            // 0..63
    int lk = (t & 3) * 4;       // 0,4,8,12
    int ty = t >> 4, tx = t & 15;
    float acc[4][4] = {};

    for (int k0 = 0; k0 < DMODEL; k0 += 16) {
        float4 a4 = *(const float4*)(A + lr * DMODEL + k0 + lk);
        float4 b4 = *(const float4*)(B + lr * DMODEL + k0 + lk);
        __syncthreads();
        As[lk + 0][lr] = a4.x; As[lk + 1][lr] = a4.y;
        As[lk + 2][lr] = a4.z; As[lk + 3][lr] = a4.w;
        Bs[lk + 0][lr] = b4.x; Bs[lk + 1][lr] = b4.y;
        Bs[lk + 2][lr] = b4.z; Bs[lk + 3][lr] = b4.w;
        __syncthreads();
        #pragma unroll
        for (int kk = 0; kk < 16; ++kk) {
            float4 av = *(const float4*)&As[kk][ty * 4];
            float4 bv = *(const float4*)&Bs[kk][tx * 4];
            float a0 = av.x, a1 = av.y, a2 = av.z, a3 = av.w;
            acc[0][0] += a0 * bv.x; acc[0][1] += a0 * bv.y; acc[0][2] += a0 * bv.z; acc[0][3] += a0 * bv.w;
            acc[1][0] += a1 * bv.x; acc[1][1] += a1 * bv.y; acc[1][2] += a1 * bv.z; acc[1][3] += a1 * bv.w;
            acc[2][0] += a2 * bv.x; acc[2][1] += a2 * bv.y; acc[2][2] += a2 * bv.z; acc[2][3] += a2 * bv.w;
            acc[3][0] += a3 * bv.x; acc[3][1] += a3 * bv.y; acc[3][2] += a3 * bv.z; acc[3][3] += a3 * bv.w;
        }
    }
    #pragma unroll
    for (int i = 0; i < 4; ++i) {
        int row = mb * 64 + ty * 4 + i;
        float4 v4 = make_float4(acc[i][0], acc[i][1], acc[i][2], acc[i][3]);
        *(float4*)&Cout[(size_t)row * ldc + col0 + tx * 4] = v4;
    }
}

// ---------------------------------------------------------------------------
// Kernel 2: per (head, chunk) KV partial sums.
// kvc[h][c][D][dd], dd in [0,65): dd<64 = v dim, dd==64 = ones (denominator).
// 320 threads: waves 0..3 compute v-part (d = t&63, g = t>>6 owns i-range),
// wave 4 computes the ones row.
// ---------------------------------------------------------------------------
__global__ __launch_bounds__(320) void chunk_kv(
    const float* __restrict__ kb, const float* __restrict__ vb,
    float* __restrict__ kvc) {
    int h = blockIdx.x & 15, c = blockIdx.x >> 4;
    int l0 = c * CHUNK;
    __shared__ __align__(16) float ks[64][16];
    __shared__ __align__(16) float vs[64][64];
    int t = threadIdx.x;
    if (t < 256) {
        int m = t >> 2, i4 = (t & 3) * 4;
        *(float4*)&ks[m][i4] = *(const float4*)&kb[(size_t)(l0 + m) * 256 + h * 16 + i4];
        int d16 = (t & 3) * 16;
        #pragma unroll
        for (int u = 0; u < 4; ++u) {
            *(float4*)&vs[m][d16 + u * 4] =
                *(const float4*)&vb[(size_t)(l0 + m) * 1024 + h * 64 + d16 + u * 4];
        }
    }
    __syncthreads();

    size_t base = ((size_t)(h * NCHUNK + c) * DFEAT) * KVS;
    if (t < 256) {
        int d = t & 63, g = t >> 6;
        float accq[4][16] = {};
        float accl[4] = {};
        float accc = 0.f;
        for (int tt = 0; tt < 64; ++tt) {
            float w = vs[tt][d];
            float4 ki = *(const float4*)&ks[tt][g * 4];
            float kj[16];
            #pragma unroll
            for (int u = 0; u < 4; ++u) {
                float4 kk4 = *(const float4*)&ks[tt][u * 4];
                kj[u * 4 + 0] = kk4.x; kj[u * 4 + 1] = kk4.y; kj[u * 4 + 2] = kk4.z; kj[u * 4 + 3] = kk4.w;
            }
            float p0 = ki.x * w, p1 = ki.y * w, p2 = ki.z * w, p3 = ki.w * w;
            #pragma unroll
            for (int j = 0; j < 16; ++j) {
                accq[0][j] += p0 * kj[j];
                accq[1][j] += p1 * kj[j];
                accq[2][j] += p2 * kj[j];
                accq[3][j] += p3 * kj[j];
            }
            accl[0] += p0; accl[1] += p1; accl[2] += p2; accl[3] += p3;
            if (g == 0) accc += w;
        }
        #pragma unroll
        for (int a = 0; a < 4; ++a) {
            int iq = g * 4 + a;
            #pragma unroll
            for (int j = 0; j < 16; ++j) {
                int D = 17 + iq * 16 + j;
                kvc[base + (size_t)D * KVS + d] = accq[a][j] * C2F;
            }
            kvc[base + (size_t)(1 + iq) * KVS + d] = accl[a] * 0.5f;
        }
        if (g == 0) kvc[base + d] = accc;
    } else {
        int lane = t - 256;
        for (int D = lane; D < DFEAT; D += 64) {
            float s = 0.f;
            if (D == 0) {
                s = 64.f;
            } else if (D < 17) {
                int i = D - 1;
                for (int tt = 0; tt < 64; ++tt) s += ks[tt][i];
                s *= 0.5f;
            } else {
                int e = D - 17, i = e >> 4, j = e & 15;
                for (int tt = 0; tt < 64; ++tt) s += ks[tt][i] * ks[tt][j];
                s *= C2F;
            }
            kvc[base + (size_t)D * KVS + 64] = s;
        }
    }
}

// ---------------------------------------------------------------------------
// Kernel 3: exclusive prefix scan over the 16 chunks, in place.
// One thread per (h, D, dd) line. 16*273*65 = 283920 threads.
// ---------------------------------------------------------------------------
__global__ __launch_bounds__(256) void scan_kv(float* __restrict__ kvc) {
    int idx = blockIdx.x * 256 + threadIdx.x;
    const int total = NHEADS * DFEAT * 65;
    if (idx >= total) return;
    int h = idx / (DFEAT * 65);
    int r = idx % (DFEAT * 65);
    int D = r / 65, dd = r % 65;
    size_t off = ((size_t)(h * NCHUNK) * DFEAT + D) * KVS + dd;
    const size_t cs = (size_t)DFEAT * KVS;
    float run = 0.f;
    #pragma unroll
    for (int c = 0; c < NCHUNK; ++c) {
        float v = kvc[off + c * cs];
        kvc[off + c * cs] = run;
        run += v;
    }
}

// ---------------------------------------------------------------------------
// Kernel 4: per (head, chunk) attention output.
// Intra: S[l][t] = causal(1 + s/4 + s^2/32), y += S·V.
// Cross: y += qf(l) · KV_prev (273-dim), den via dd==64 column.
// Thread layout: l = t&63, g = t>>6 owns d in [16g, 16g+16).
// ---------------------------------------------------------------------------
__global__ __launch_bounds__(256) void attn(
    const float* __restrict__ qb, const float* __restrict__ kb,
    const float* __restrict__ vb, const float* __restrict__ kvc,
    float* __restrict__ yb) {
    int h = blockIdx.x & 15, c = blockIdx.x >> 4;
    int l0 = c * CHUNK;
    __shared__ float qs[64][17];
    __shared__ float ks2[64][17];
    __shared__ __align__(16) float vs[64][64];
    __shared__ float SS[64][65];
    __shared__ float dens[64];
    int t = threadIdx.x;
    {
        int m = t >> 2, i4 = (t & 3) * 4;
        float4 a = *(const float4*)&qb[(size_t)(l0 + m) * 256 + h * 16 + i4];
        qs[m][i4] = a.x; qs[m][i4 + 1] = a.y; qs[m][i4 + 2] = a.z; qs[m][i4 + 3] = a.w;
        float4 b = *(const float4*)&kb[(size_t)(l0 + m) * 256 + h * 16 + i4];
        ks2[m][i4] = b.x; ks2[m][i4 + 1] = b.y; ks2[m][i4 + 2] = b.z; ks2[m][i4 + 3] = b.w;
        int d16 = (t & 3) * 16;
        #pragma unroll
        for (int u = 0; u < 4; ++u) {
            *(float4*)&vs[m][d16 + u * 4] =
                *(const float4*)&vb[(size_t)(l0 + m) * 1024 + h * 64 + d16 + u * 4];
        }
    }
    __syncthreads();
    // build causal score matrix
    for (int e = t; e < 64 * 64; e += 256) {
        int l = e >> 6, tt = e & 63;
        float s = 0.f;
        #pragma unroll
        for (int i = 0; i < 16; ++i) s += qs[l][i] * ks2[tt][i];
        SS[l][tt] = (tt <= l) ? (1.f + 0.25f * s + 0.03125f * s * s) : 0.f;
    }
    __syncthreads();

    int l = t & 63, g = t >> 6;
    const float* kvbase = kvc + ((size_t)(h * NCHUNK + c) * DFEAT) * KVS;
    float acc[16] = {};
    float den = 0.f;

    auto addD = [&](int D, float qf) {
        const float* p = kvbase + (size_t)D * KVS + g * 16;
        float4 r0 = *(const float4*)p;
        float4 r1 = *(const float4*)(p + 4);
        float4 r2 = *(const float4*)(p + 8);
        float4 r3 = *(const float4*)(p + 12);
        acc[0]  += qf * r0.x; acc[1]  += qf * r0.y; acc[2]  += qf * r0.z; acc[3]  += qf * r0.w;
        acc[4]  += qf * r1.x; acc[5]  += qf * r1.y; acc[6]  += qf * r1.z; acc[7]  += qf * r1.w;
        acc[8]  += qf * r2.x; acc[9]  += qf * r2.y; acc[10] += qf * r2.z; acc[11] += qf * r2.w;
        acc[12] += qf * r3.x; acc[13] += qf * r3.y; acc[14] += qf * r3.z; acc[15] += qf * r3.w;
        if (g == 0) den += qf * p[64];   // g==0: p points at D*KVS, +64 is the ones column
    };

    addD(0, 1.f);
    #pragma unroll
    for (int j = 0; j < 16; ++j) addD(1 + j, qs[l][j] * 0.5f);
    for (int i = 0; i < 16; ++i) {
        float qi = qs[l][i] * C2F;
        #pragma unroll
        for (int j = 0; j < 16; ++j) addD(17 + i * 16 + j, qi * qs[l][j]);
    }
    // intra-chunk
    for (int tt = 0; tt < 64; ++tt) {
        float sv = SS[l][tt];
        if (g == 0) den += sv;
        const float* vr = &vs[tt][g * 16];
        float4 v0 = *(const float4*)vr;
        float4 v1 = *(const float4*)(vr + 4);
        float4 v2 = *(const float4*)(vr + 8);
        float4 v3 = *(const float4*)(vr + 12);
        acc[0]  += sv * v0.x; acc[1]  += sv * v0.y; acc[2]  += sv * v0.z; acc[3]  += sv * v0.w;
        acc[4]  += sv * v1.x; acc[5]  += sv * v1.y; acc[6]  += sv * v1.z; acc[7]  += sv * v1.w;
        acc[8]  += sv * v2.x; acc[9]  += sv * v2.y; acc[10] += sv * v2.z; acc[11] += sv * v2.w;
        acc[12] += sv * v3.x; acc[13] += sv * v3.y; acc[14] += sv * v3.z; acc[15] += sv * v3.w;
    }
    if (g == 0) dens[l] = den + 1e-12f;
    __syncthreads();
    float dinv = 1.f / dens[l];
    float* yp = &yb[(size_t)(l0 + l) * 1024 + h * 64 + g * 16];
    #pragma unroll
    for (int u = 0; u < 4; ++u) {
        float4 o = make_float4(acc[u * 4 + 0] * dinv, acc[u * 4 + 1] * dinv,
                               acc[u * 4 + 2] * dinv, acc[u * 4 + 3] * dinv);
        *(float4*)&yp[u * 4] = o;
    }
}

// ---------------------------------------------------------------------------
// Kernel 5: output projection. out = y @ Wo^T. y fp32, Wo fp32.
// Output dtype chosen at runtime by flag: fp32 or bf16.
// ---------------------------------------------------------------------------
__global__ __launch_bounds__(256) void out_proj(
    const float* __restrict__ A, const float* __restrict__ Bw,
    void* __restrict__ outv, const int* __restrict__ flagp) {
    int nb = blockIdx.x, mb = blockIdx.y;
    const float* B = Bw + (size_t)nb * 64 * DMODEL;
    const float* Ab = A + (size_t)mb * 64 * DMODEL;

    __shared__ __align__(16) float As[16][64];
    __shared__ __align__(16) float Bs[16][64];
    int t = threadIdx.x;
    int lr = t >> 2;
    int lk = (t & 3) * 4;
    int ty = t >> 4, tx = t & 15;
    float acc[4][4] = {};

    for (int k0 = 0; k0 < DMODEL; k0 += 16) {
        float4 a4 = *(const float4*)(Ab + lr * DMODEL + k0 + lk);
        float4 b4 = *(const float4*)(B + lr * DMODEL + k0 + lk);
        __syncthreads();
        As[lk + 0][lr] = a4.x; As[lk + 1][lr] = a4.y;
        As[lk + 2][lr] = a4.z; As[lk + 3][lr] = a4.w;
        Bs[lk + 0][lr] = b4.x; Bs[lk + 1][lr] = b4.y;
        Bs[lk + 2][lr] = b4.z; Bs[lk + 3][lr] = b4.w;
        __syncthreads();
        #pragma unroll
        for (int kk = 0; kk < 16; ++kk) {
            float4 av = *(const float4*)&As[kk][ty * 4];
            float4 bv = *(const float4*)&Bs[kk][tx * 4];
            float a0 = av.x, a1 = av.y, a2 = av.z, a3 = av.w;
            acc[0][0] += a0 * bv.x; acc[0][1] += a0 * bv.y; acc[0][2] += a0 * bv.z; acc[0][3] += a0 * bv.w;
            acc[1][0] += a1 * bv.x; acc[1][1] += a1 * bv.y; acc[1][2] += a1 * bv.z; acc[1][3] += a1 * bv.w;
            acc[2][0] += a2 * bv.x; acc[2][1] += a2 * bv.y; acc[2][2] += a2 * bv.z; acc[2][3] += a2 * bv.w;
            acc[3][0] += a3 * bv.x; acc[3][1] += a3 * bv.y; acc[3][2] += a3 * bv.z; acc[3][3] += a3 * bv.w;
        }
    }
    int fp32 = *flagp;
    #pragma unroll
    for (int i = 0; i < 4; ++i) {
        int row = mb * 64 + ty * 4 + i;
        size_t idx = (size_t)row * 1024 + nb * 64 + tx * 4;
        if (fp32) {
            float4 v4 = make_float4(acc[i][0], acc[i][1], acc[i][2], acc[i][3]);
            *(float4*)((float*)outv + idx) = v4;
        } else {
            ushort4 o;
            o.x = f2bf(acc[i][0]); o.y = f2bf(acc[i][1]);
            o.z = f2bf(acc[i][2]); o.w = f2bf(acc[i][3]);
            *(ushort4*)((unsigned short*)outv + idx) = o;
        }
    }
}

// ---------------------------------------------------------------------------
extern "C" void kernel_launch(void* const* d_in, const int* in_sizes, int n_in,
                              void* d_out, int out_size, void* d_ws, size_t ws_size,
                              hipStream_t stream) {
    float* ws = (float*)d_ws;
    float* hidF = ws + OFF_HID;
    float* WqF  = ws + OFF_WQ;
    float* WkF  = ws + OFF_WK;
    float* WvF  = ws + OFF_WV;
    float* WoF  = ws + OFF_WO;
    float* qb   = ws + OFF_QB;
    float* kb   = ws + OFF_KB;
    float* vb   = ws + OFF_VB;
    float* yb   = ws + OFF_YB;
    float* kvc  = ws + OFF_KVC;
    int*   flag = (int*)(ws + OFF_FLAG);
    size_t need = (size_t)(OFF_FLAG + 1) * 4ull;
    if (ws_size < need) return;

    detect_dtype<<<dim3(1), 256, 0, stream>>>((const unsigned short*)d_in[1], flag);
    convert_inputs<<<dim3(3584), 256, 0, stream>>>(d_in[0], d_in[1], d_in[2], d_in[3], d_in[4], ws, flag);
    qkv_proj<<<dim3(24, 16), 256, 0, stream>>>(hidF, WqF, WkF, WvF, qb, kb, vb);
    chunk_kv<<<dim3(256), 320, 0, stream>>>(kb, vb, kvc);
    scan_kv<<<dim3(1110), 256, 0, stream>>>(kvc);
    attn<<<dim3(256), 256, 0, stream>>>(qb, kb, vb, kvc, yb);
    out_proj<<<dim3(16, 16), 256, 0, stream>>>(yb, WoF, d_out, flag);
}

// Round 3
// 215.099 us; speedup vs baseline: 1.3446x; 1.3446x over previous
//
#include <hip/hip_runtime.h>

// Problem constants
#define LSEQ 1024
#define DMODEL 1024
#define NHEADS 16
#define FDIM 16
#define HDIM 64
#define DFEAT 273          // 1 + 16 + 256
#define CHUNK 64
#define NCHUNK 16
#define KVS 68             // padded row stride for kvc inner dim (65 used, 68 for 16B align)

typedef __attribute__((ext_vector_type(8))) short short8;   // 8 bf16 (4 VGPRs)
typedef __attribute__((ext_vector_type(4))) float floatx4;  // MFMA acc

__device__ __forceinline__ float bf2f(unsigned short u) {
    unsigned int x = ((unsigned int)u) << 16;
    return __builtin_bit_cast(float, x);
}
__device__ __forceinline__ unsigned short f2bf(float f) {
    unsigned int x = __builtin_bit_cast(unsigned int, f);
    unsigned int r = (x + 0x7fffu + ((x >> 16) & 1u)) >> 16;
    return (unsigned short)r;
}

#define C2F 0.17677669529663687f   // 1/(4*sqrt(2))

// Workspace layout.
// bf16 (ushort) region, contiguous so convert kernel writes base+e directly:
//   hidB  @0        (1048576)   1024x1024
//   wqkvB @1048576  (1572864)   rows: 0..255 Wq, 256..511 Wk, 512..1535 Wv
//   woB   @2621440  (1048576)   1024x1024
//   ybB   @3670016  (1048576)   1024x1024 (attn output, bf16)
// fp32 region starts at float index F0 = 2359296 (= 9437184 bytes / 4):
//   qb  @F0          (262144)
//   kb  @F0+262144   (262144)
//   vb  @F0+524288   (1048576)
//   kvc @F0+1572864  (4752384)
//   flag@F0+6325248  (1 int)
#define U_HID  0
#define U_WQKV 1048576
#define U_WO   2621440
#define U_YB   3670016
#define F0     2359296
#define F_QB   (F0)
#define F_KB   (F0 + 262144)
#define F_VB   (F0 + 524288)
#define F_KVC  (F0 + 1572864)
#define F_FLAG (F0 + 6325248)
#define NCONVB 3670016   // hid + Wq + Wk + Wv + Wo elements

// ---------------------------------------------------------------------------
// Kernel 0: dtype detector (flag=1 means inputs are fp32).
// ---------------------------------------------------------------------------
__global__ void detect_dtype(const unsigned short* __restrict__ wq, int* __restrict__ flag) {
    __shared__ int cnt;
    if (threadIdx.x == 0) cnt = 0;
    __syncthreads();
    int bad = 0;
    for (int i = threadIdx.x; i < 2048; i += 256) {
        int e = (wq[i] >> 7) & 0xFF;
        if (e >= 143 || (e > 0 && e <= 80)) bad++;
    }
    atomicAdd(&cnt, bad);
    __syncthreads();
    if (threadIdx.x == 0) *flag = (cnt > 256) ? 1 : 0;
}

// ---------------------------------------------------------------------------
// Kernel 0b: materialize all five inputs as packed bf16 in ws.
// 8 elements/thread; 1792 blocks x 256 thr x 8 = 3,670,016 exactly.
// ---------------------------------------------------------------------------
__global__ __launch_bounds__(256) void convert_bf16(
    const void* __restrict__ s0, const void* __restrict__ s1,
    const void* __restrict__ s2, const void* __restrict__ s3,
    const void* __restrict__ s4, unsigned short* __restrict__ dst,
    const int* __restrict__ flagp) {
    int fp32 = *flagp;
    size_t e = ((size_t)blockIdx.x * 256 + threadIdx.x) * 8;
    if (e >= NCONVB) return;
    const void* src; size_t off;
    if (e < 1048576)      { src = s0; off = e; }
    else if (e < 1310720) { src = s1; off = e - 1048576; }
    else if (e < 1572864) { src = s2; off = e - 1310720; }
    else if (e < 2621440) { src = s3; off = e - 1572864; }
    else                  { src = s4; off = e - 2621440; }
    if (fp32) {
        const float* f = (const float*)src + off;
        float4 v0 = *(const float4*)f;
        float4 v1 = *(const float4*)(f + 4);
        ushort4 o0, o1;
        o0.x = f2bf(v0.x); o0.y = f2bf(v0.y); o0.z = f2bf(v0.z); o0.w = f2bf(v0.w);
        o1.x = f2bf(v1.x); o1.y = f2bf(v1.y); o1.z = f2bf(v1.z); o1.w = f2bf(v1.w);
        *(ushort4*)(dst + e) = o0;
        *(ushort4*)(dst + e + 4) = o1;
    } else {
        const unsigned short* u = (const unsigned short*)src + off;
        *(ushort4*)(dst + e) = *(const ushort4*)u;
        *(ushort4*)(dst + e + 4) = *(const ushort4*)(u + 4);
    }
}

// ---------------------------------------------------------------------------
// Kernel 1: QKV projection via bf16 MFMA. C = hid @ [Wq;Wk;Wv]^T.
// M=1024, N=1536, K=1024. Block = 64x64 C-tile, 4 waves in 2x2, each wave
// 32x32 (2x2 MFMA 16x16x32 tiles). Fragments loaded straight from global
// (K-contiguous 16B per lane); L1/L2 provide reuse.
// A-frag: lane holds A[m=lane&15][k = (lane>>4)*8 + j]; B symmetric.
// C/D: col = lane&15, row = (lane>>4)*4 + reg  [measured: learn_hip m89].
// Output columns: 0..255 -> qb (ld 256), 256..511 -> kb, 512..1535 -> vb.
// ---------------------------------------------------------------------------
__global__ __launch_bounds__(256) void qkv_mfma(
    const unsigned short* __restrict__ A, const unsigned short* __restrict__ B,
    float* __restrict__ qb, float* __restrict__ kb, float* __restrict__ vb) {
    int t = threadIdx.x;
    int wave = t >> 6, lane = t & 63;
    int m_l = lane & 15, q4 = lane >> 4;
    int m0 = blockIdx.y * 64 + (wave >> 1) * 32;
    int n0 = blockIdx.x * 64 + (wave & 1) * 32;

    const unsigned short* a0p = A + (size_t)(m0 + m_l) * DMODEL + q4 * 8;
    const unsigned short* a1p = a0p + 16 * DMODEL;
    const unsigned short* b0p = B + (size_t)(n0 + m_l) * DMODEL + q4 * 8;
    const unsigned short* b1p = b0p + 16 * DMODEL;

    floatx4 acc00 = {0.f,0.f,0.f,0.f}, acc01 = acc00, acc10 = acc00, acc11 = acc00;
    #pragma unroll 4
    for (int k0 = 0; k0 < DMODEL; k0 += 32) {
        short8 a0 = *(const short8*)(a0p + k0);
        short8 a1 = *(const short8*)(a1p + k0);
        short8 b0 = *(const short8*)(b0p + k0);
        short8 b1 = *(const short8*)(b1p + k0);
        acc00 = __builtin_amdgcn_mfma_f32_16x16x32_bf16(a0, b0, acc00, 0, 0, 0);
        acc01 = __builtin_amdgcn_mfma_f32_16x16x32_bf16(a0, b1, acc01, 0, 0, 0);
        acc10 = __builtin_amdgcn_mfma_f32_16x16x32_bf16(a1, b0, acc10, 0, 0, 0);
        acc11 = __builtin_amdgcn_mfma_f32_16x16x32_bf16(a1, b1, acc11, 0, 0, 0);
    }

    #pragma unroll
    for (int mi = 0; mi < 2; ++mi) {
        #pragma unroll
        for (int ni = 0; ni < 2; ++ni) {
            floatx4 acc = mi == 0 ? (ni == 0 ? acc00 : acc01) : (ni == 0 ? acc10 : acc11);
            int n = n0 + ni * 16 + m_l;
            #pragma unroll
            for (int r = 0; r < 4; ++r) {
                int row = m0 + mi * 16 + q4 * 4 + r;
                float v = acc[r];
                if (n < 256)      qb[(size_t)row * 256 + n] = v;
                else if (n < 512) kb[(size_t)row * 256 + (n - 256)] = v;
                else              vb[(size_t)row * 1024 + (n - 512)] = v;
            }
        }
    }
}

// ---------------------------------------------------------------------------
// Kernel 2: per (head, chunk) KV partial sums (fp32 VALU, unchanged).
// ---------------------------------------------------------------------------
__global__ __launch_bounds__(320) void chunk_kv(
    const float* __restrict__ kb, const float* __restrict__ vb,
    float* __restrict__ kvc) {
    int h = blockIdx.x & 15, c = blockIdx.x >> 4;
    int l0 = c * CHUNK;
    __shared__ __align__(16) float ks[64][16];
    __shared__ __align__(16) float vs[64][64];
    int t = threadIdx.x;
    if (t < 256) {
        int m = t >> 2, i4 = (t & 3) * 4;
        *(float4*)&ks[m][i4] = *(const float4*)&kb[(size_t)(l0 + m) * 256 + h * 16 + i4];
        int d16 = (t & 3) * 16;
        #pragma unroll
        for (int u = 0; u < 4; ++u) {
            *(float4*)&vs[m][d16 + u * 4] =
                *(const float4*)&vb[(size_t)(l0 + m) * 1024 + h * 64 + d16 + u * 4];
        }
    }
    __syncthreads();

    size_t base = ((size_t)(h * NCHUNK + c) * DFEAT) * KVS;
    if (t < 256) {
        int d = t & 63, g = t >> 6;
        float accq[4][16] = {};
        float accl[4] = {};
        float accc = 0.f;
        for (int tt = 0; tt < 64; ++tt) {
            float w = vs[tt][d];
            float4 ki = *(const float4*)&ks[tt][g * 4];
            float kj[16];
            #pragma unroll
            for (int u = 0; u < 4; ++u) {
                float4 kk4 = *(const float4*)&ks[tt][u * 4];
                kj[u * 4 + 0] = kk4.x; kj[u * 4 + 1] = kk4.y; kj[u * 4 + 2] = kk4.z; kj[u * 4 + 3] = kk4.w;
            }
            float p0 = ki.x * w, p1 = ki.y * w, p2 = ki.z * w, p3 = ki.w * w;
            #pragma unroll
            for (int j = 0; j < 16; ++j) {
                accq[0][j] += p0 * kj[j];
                accq[1][j] += p1 * kj[j];
                accq[2][j] += p2 * kj[j];
                accq[3][j] += p3 * kj[j];
            }
            accl[0] += p0; accl[1] += p1; accl[2] += p2; accl[3] += p3;
            if (g == 0) accc += w;
        }
        #pragma unroll
        for (int a = 0; a < 4; ++a) {
            int iq = g * 4 + a;
            #pragma unroll
            for (int j = 0; j < 16; ++j) {
                int D = 17 + iq * 16 + j;
                kvc[base + (size_t)D * KVS + d] = accq[a][j] * C2F;
            }
            kvc[base + (size_t)(1 + iq) * KVS + d] = accl[a] * 0.5f;
        }
        if (g == 0) kvc[base + d] = accc;
    } else {
        int lane = t - 256;
        for (int D = lane; D < DFEAT; D += 64) {
            float s = 0.f;
            if (D == 0) {
                s = 64.f;
            } else if (D < 17) {
                int i = D - 1;
                for (int tt = 0; tt < 64; ++tt) s += ks[tt][i];
                s *= 0.5f;
            } else {
                int e = D - 17, i = e >> 4, j = e & 15;
                for (int tt = 0; tt < 64; ++tt) s += ks[tt][i] * ks[tt][j];
                s *= C2F;
            }
            kvc[base + (size_t)D * KVS + 64] = s;
        }
    }
}

// ---------------------------------------------------------------------------
// Kernel 3: exclusive prefix scan over the 16 chunks, in place.
// ---------------------------------------------------------------------------
__global__ __launch_bounds__(256) void scan_kv(float* __restrict__ kvc) {
    int idx = blockIdx.x * 256 + threadIdx.x;
    const int total = NHEADS * DFEAT * 65;
    if (idx >= total) return;
    int h = idx / (DFEAT * 65);
    int r = idx % (DFEAT * 65);
    int D = r / 65, dd = r % 65;
    size_t off = ((size_t)(h * NCHUNK) * DFEAT + D) * KVS + dd;
    const size_t cs = (size_t)DFEAT * KVS;
    float run = 0.f;
    #pragma unroll
    for (int c = 0; c < NCHUNK; ++c) {
        float v = kvc[off + c * cs];
        kvc[off + c * cs] = run;
        run += v;
    }
}

// ---------------------------------------------------------------------------
// Kernel 4: per (head, chunk) attention output; now writes y as bf16.
// ---------------------------------------------------------------------------
__global__ __launch_bounds__(256) void attn(
    const float* __restrict__ qb, const float* __restrict__ kb,
    const float* __restrict__ vb, const float* __restrict__ kvc,
    unsigned short* __restrict__ ybB) {
    int h = blockIdx.x & 15, c = blockIdx.x >> 4;
    int l0 = c * CHUNK;
    __shared__ float qs[64][17];
    __shared__ float ks2[64][17];
    __shared__ __align__(16) float vs[64][64];
    __shared__ float SS[64][65];
    __shared__ float dens[64];
    int t = threadIdx.x;
    {
        int m = t >> 2, i4 = (t & 3) * 4;
        float4 a = *(const float4*)&qb[(size_t)(l0 + m) * 256 + h * 16 + i4];
        qs[m][i4] = a.x; qs[m][i4 + 1] = a.y; qs[m][i4 + 2] = a.z; qs[m][i4 + 3] = a.w;
        float4 b = *(const float4*)&kb[(size_t)(l0 + m) * 256 + h * 16 + i4];
        ks2[m][i4] = b.x; ks2[m][i4 + 1] = b.y; ks2[m][i4 + 2] = b.z; ks2[m][i4 + 3] = b.w;
        int d16 = (t & 3) * 16;
        #pragma unroll
        for (int u = 0; u < 4; ++u) {
            *(float4*)&vs[m][d16 + u * 4] =
                *(const float4*)&vb[(size_t)(l0 + m) * 1024 + h * 64 + d16 + u * 4];
        }
    }
    __syncthreads();
    for (int e = t; e < 64 * 64; e += 256) {
        int l = e >> 6, tt = e & 63;
        float s = 0.f;
        #pragma unroll
        for (int i = 0; i < 16; ++i) s += qs[l][i] * ks2[tt][i];
        SS[l][tt] = (tt <= l) ? (1.f + 0.25f * s + 0.03125f * s * s) : 0.f;
    }
    __syncthreads();

    int l = t & 63, g = t >> 6;
    const float* kvbase = kvc + ((size_t)(h * NCHUNK + c) * DFEAT) * KVS;
    float acc[16] = {};
    float den = 0.f;

    auto addD = [&](int D, float qf) {
        const float* p = kvbase + (size_t)D * KVS + g * 16;
        float4 r0 = *(const float4*)p;
        float4 r1 = *(const float4*)(p + 4);
        float4 r2 = *(const float4*)(p + 8);
        float4 r3 = *(const float4*)(p + 12);
        acc[0]  += qf * r0.x; acc[1]  += qf * r0.y; acc[2]  += qf * r0.z; acc[3]  += qf * r0.w;
        acc[4]  += qf * r1.x; acc[5]  += qf * r1.y; acc[6]  += qf * r1.z; acc[7]  += qf * r1.w;
        acc[8]  += qf * r2.x; acc[9]  += qf * r2.y; acc[10] += qf * r2.z; acc[11] += qf * r2.w;
        acc[12] += qf * r3.x; acc[13] += qf * r3.y; acc[14] += qf * r3.z; acc[15] += qf * r3.w;
        if (g == 0) den += qf * p[64];
    };

    addD(0, 1.f);
    #pragma unroll
    for (int j = 0; j < 16; ++j) addD(1 + j, qs[l][j] * 0.5f);
    for (int i = 0; i < 16; ++i) {
        float qi = qs[l][i] * C2F;
        #pragma unroll
        for (int j = 0; j < 16; ++j) addD(17 + i * 16 + j, qi * qs[l][j]);
    }
    for (int tt = 0; tt < 64; ++tt) {
        float sv = SS[l][tt];
        if (g == 0) den += sv;
        const float* vr = &vs[tt][g * 16];
        float4 v0 = *(const float4*)vr;
        float4 v1 = *(const float4*)(vr + 4);
        float4 v2 = *(const float4*)(vr + 8);
        float4 v3 = *(const float4*)(vr + 12);
        acc[0]  += sv * v0.x; acc[1]  += sv * v0.y; acc[2]  += sv * v0.z; acc[3]  += sv * v0.w;
        acc[4]  += sv * v1.x; acc[5]  += sv * v1.y; acc[6]  += sv * v1.z; acc[7]  += sv * v1.w;
        acc[8]  += sv * v2.x; acc[9]  += sv * v2.y; acc[10] += sv * v2.z; acc[11] += sv * v2.w;
        acc[12] += sv * v3.x; acc[13] += sv * v3.y; acc[14] += sv * v3.z; acc[15] += sv * v3.w;
    }
    if (g == 0) dens[l] = den + 1e-12f;
    __syncthreads();
    float dinv = 1.f / dens[l];
    unsigned short* yp = ybB + (size_t)(l0 + l) * 1024 + h * 64 + g * 16;
    #pragma unroll
    for (int u = 0; u < 4; ++u) {
        ushort4 o;
        o.x = f2bf(acc[u * 4 + 0] * dinv); o.y = f2bf(acc[u * 4 + 1] * dinv);
        o.z = f2bf(acc[u * 4 + 2] * dinv); o.w = f2bf(acc[u * 4 + 3] * dinv);
        *(ushort4*)(yp + u * 4) = o;
    }
}

// ---------------------------------------------------------------------------
// Kernel 5: output projection via bf16 MFMA. out = y @ Wo^T (M=N=K=1024).
// Same tiling as qkv_mfma. Output dtype per flag.
// ---------------------------------------------------------------------------
__global__ __launch_bounds__(256) void out_mfma(
    const unsigned short* __restrict__ A, const unsigned short* __restrict__ B,
    void* __restrict__ outv, const int* __restrict__ flagp) {
    int t = threadIdx.x;
    int wave = t >> 6, lane = t & 63;
    int m_l = lane & 15, q4 = lane >> 4;
    int m0 = blockIdx.y * 64 + (wave >> 1) * 32;
    int n0 = blockIdx.x * 64 + (wave & 1) * 32;

    const unsigned short* a0p = A + (size_t)(m0 + m_l) * DMODEL + q4 * 8;
    const unsigned short* a1p = a0p + 16 * DMODEL;
    const unsigned short* b0p = B + (size_t)(n0 + m_l) * DMODEL + q4 * 8;
    const unsigned short* b1p = b0p + 16 * DMODEL;

    floatx4 acc00 = {0.f,0.f,0.f,0.f}, acc01 = acc00, acc10 = acc00, acc11 = acc00;
    #pragma unroll 4
    for (int k0 = 0; k0 < DMODEL; k0 += 32) {
        short8 a0 = *(const short8*)(a0p + k0);
        short8 a1 = *(const short8*)(a1p + k0);
        short8 b0 = *(const short8*)(b0p + k0);
        short8 b1 = *(const short8*)(b1p + k0);
        acc00 = __builtin_amdgcn_mfma_f32_16x16x32_bf16(a0, b0, acc00, 0, 0, 0);
        acc01 = __builtin_amdgcn_mfma_f32_16x16x32_bf16(a0, b1, acc01, 0, 0, 0);
        acc10 = __builtin_amdgcn_mfma_f32_16x16x32_bf16(a1, b0, acc10, 0, 0, 0);
        acc11 = __builtin_amdgcn_mfma_f32_16x16x32_bf16(a1, b1, acc11, 0, 0, 0);
    }
    int fp32 = *flagp;
    #pragma unroll
    for (int mi = 0; mi < 2; ++mi) {
        #pragma unroll
        for (int ni = 0; ni < 2; ++ni) {
            floatx4 acc = mi == 0 ? (ni == 0 ? acc00 : acc01) : (ni == 0 ? acc10 : acc11);
            int n = n0 + ni * 16 + m_l;
            #pragma unroll
            for (int r = 0; r < 4; ++r) {
                int row = m0 + mi * 16 + q4 * 4 + r;
                size_t idx = (size_t)row * 1024 + n;
                if (fp32) ((float*)outv)[idx] = acc[r];
                else      ((unsigned short*)outv)[idx] = f2bf(acc[r]);
            }
        }
    }
}

// ---------------------------------------------------------------------------
extern "C" void kernel_launch(void* const* d_in, const int* in_sizes, int n_in,
                              void* d_out, int out_size, void* d_ws, size_t ws_size,
                              hipStream_t stream) {
    unsigned short* us = (unsigned short*)d_ws;
    float* ws = (float*)d_ws;
    unsigned short* hidB  = us + U_HID;
    unsigned short* wqkvB = us + U_WQKV;
    unsigned short* woB   = us + U_WO;
    unsigned short* ybB   = us + U_YB;
    float* qb  = ws + F_QB;
    float* kb  = ws + F_KB;
    float* vb  = ws + F_VB;
    float* kvc = ws + F_KVC;
    int*  flag = (int*)(ws + F_FLAG);
    size_t need = (size_t)(F_FLAG + 1) * 4ull;
    if (ws_size < need) return;

    detect_dtype<<<dim3(1), 256, 0, stream>>>((const unsigned short*)d_in[1], flag);
    convert_bf16<<<dim3(1792), 256, 0, stream>>>(d_in[0], d_in[1], d_in[2], d_in[3], d_in[4], us, flag);
    qkv_mfma<<<dim3(24, 16), 256, 0, stream>>>(hidB, wqkvB, qb, kb, vb);
    chunk_kv<<<dim3(256), 320, 0, stream>>>(kb, vb, kvc);
    scan_kv<<<dim3(1110), 256, 0, stream>>>(kvc);
    attn<<<dim3(256), 256, 0, stream>>>(qb, kb, vb, kvc, ybB);
    out_mfma<<<dim3(16, 16), 256, 0, stream>>>(ybB, woB, d_out, flag);
}

// Round 4
// 182.807 us; speedup vs baseline: 1.5821x; 1.1766x over previous
//
#include <hip/hip_runtime.h>

// Problem constants
#define LSEQ 1024
#define DMODEL 1024
#define NHEADS 16
#define FDIM 16
#define HDIM 64
#define DFEAT 273          // 1 + 16 + 256
#define CHUNK 64
#define NCHUNK 16
#define DPAD 288           // DFEAT padded to multiple of 32 for MFMA K
#define C2F 0.17677669529663687f   // 1/(4*sqrt(2))

typedef __attribute__((ext_vector_type(8))) short short8;   // 8 bf16 (4 VGPRs)
typedef __attribute__((ext_vector_type(4))) float floatx4;  // MFMA acc

__device__ __forceinline__ float bf2f(unsigned short u) {
    unsigned int x = ((unsigned int)u) << 16;
    return __builtin_bit_cast(float, x);
}
__device__ __forceinline__ unsigned short f2bf(float f) {
    unsigned int x = __builtin_bit_cast(unsigned int, f);
    unsigned int r = (x + 0x7fffu + ((x >> 16) & 1u)) >> 16;
    return (unsigned short)r;
}

// Workspace layout (ushort indices unless noted):
//   hidB  @0         (1048576)
//   wqkvB @1048576   (1572864)  rows 0..255 Wq, 256..511 Wk, 512..1535 Wv
//   woB   @2621440   (1048576)
//   ybB   @3670016   (1048576)
//   qbB   @4718592   (262144)   bf16 q  [1024][256]
//   kbB   @4980736   (262144)   bf16 k  [1024][256]
//   vbB   @5242880   (1048576)  bf16 v  [1024][1024]
//   kvtB  @6291456   (5898240)  bf16 KV exclusive prefix [h][c][80][288]
// float region F0 = 6094848 (float idx):
//   kvp  @F0         (4792320)  fp32 KV chunk partials [h][c][65][288]
//   flag @10887168
#define U_HID  0
#define U_WQKV 1048576
#define U_WO   2621440
#define U_YB   3670016
#define U_QB   4718592
#define U_KB   4980736
#define U_VB   5242880
#define U_KVT  6291456
#define F0     6094848
#define F_KVP  F0
#define F_FLAG 10887168
#define NCONVB 3670016

// ---------------------------------------------------------------------------
// Kernel 0: dtype detector (flag=1 means inputs are fp32).
// ---------------------------------------------------------------------------
__global__ void detect_dtype(const unsigned short* __restrict__ wq, int* __restrict__ flag) {
    __shared__ int cnt;
    if (threadIdx.x == 0) cnt = 0;
    __syncthreads();
    int bad = 0;
    for (int i = threadIdx.x; i < 2048; i += 256) {
        int e = (wq[i] >> 7) & 0xFF;
        if (e >= 143 || (e > 0 && e <= 80)) bad++;
    }
    atomicAdd(&cnt, bad);
    __syncthreads();
    if (threadIdx.x == 0) *flag = (cnt > 256) ? 1 : 0;
}

// ---------------------------------------------------------------------------
// Kernel 0b: materialize all five inputs as packed bf16 in ws.
// ---------------------------------------------------------------------------
__global__ __launch_bounds__(256) void convert_bf16(
    const void* __restrict__ s0, const void* __restrict__ s1,
    const void* __restrict__ s2, const void* __restrict__ s3,
    const void* __restrict__ s4, unsigned short* __restrict__ dst,
    const int* __restrict__ flagp) {
    int fp32 = *flagp;
    size_t e = ((size_t)blockIdx.x * 256 + threadIdx.x) * 8;
    if (e >= NCONVB) return;
    const void* src; size_t off;
    if (e < 1048576)      { src = s0; off = e; }
    else if (e < 1310720) { src = s1; off = e - 1048576; }
    else if (e < 1572864) { src = s2; off = e - 1310720; }
    else if (e < 2621440) { src = s3; off = e - 1572864; }
    else                  { src = s4; off = e - 2621440; }
    if (fp32) {
        const float* f = (const float*)src + off;
        float4 v0 = *(const float4*)f;
        float4 v1 = *(const float4*)(f + 4);
        ushort4 o0, o1;
        o0.x = f2bf(v0.x); o0.y = f2bf(v0.y); o0.z = f2bf(v0.z); o0.w = f2bf(v0.w);
        o1.x = f2bf(v1.x); o1.y = f2bf(v1.y); o1.z = f2bf(v1.z); o1.w = f2bf(v1.w);
        *(ushort4*)(dst + e) = o0;
        *(ushort4*)(dst + e + 4) = o1;
    } else {
        const unsigned short* u = (const unsigned short*)src + off;
        *(ushort4*)(dst + e) = *(const ushort4*)u;
        *(ushort4*)(dst + e + 4) = *(const ushort4*)(u + 4);
    }
}

// ---------------------------------------------------------------------------
// Kernel 1: QKV projection via bf16 MFMA; outputs bf16 q/k/v.
// ---------------------------------------------------------------------------
__global__ __launch_bounds__(256) void qkv_mfma(
    const unsigned short* __restrict__ A, const unsigned short* __restrict__ B,
    unsigned short* __restrict__ qb, unsigned short* __restrict__ kb,
    unsigned short* __restrict__ vb) {
    int t = threadIdx.x;
    int wave = t >> 6, lane = t & 63;
    int m_l = lane & 15, q4 = lane >> 4;
    int m0 = blockIdx.y * 64 + (wave >> 1) * 32;
    int n0 = blockIdx.x * 64 + (wave & 1) * 32;

    const unsigned short* a0p = A + (size_t)(m0 + m_l) * DMODEL + q4 * 8;
    const unsigned short* a1p = a0p + 16 * DMODEL;
    const unsigned short* b0p = B + (size_t)(n0 + m_l) * DMODEL + q4 * 8;
    const unsigned short* b1p = b0p + 16 * DMODEL;

    floatx4 acc00 = {0.f,0.f,0.f,0.f}, acc01 = acc00, acc10 = acc00, acc11 = acc00;
    #pragma unroll 4
    for (int k0 = 0; k0 < DMODEL; k0 += 32) {
        short8 a0 = *(const short8*)(a0p + k0);
        short8 a1 = *(const short8*)(a1p + k0);
        short8 b0 = *(const short8*)(b0p + k0);
        short8 b1 = *(const short8*)(b1p + k0);
        acc00 = __builtin_amdgcn_mfma_f32_16x16x32_bf16(a0, b0, acc00, 0, 0, 0);
        acc01 = __builtin_amdgcn_mfma_f32_16x16x32_bf16(a0, b1, acc01, 0, 0, 0);
        acc10 = __builtin_amdgcn_mfma_f32_16x16x32_bf16(a1, b0, acc10, 0, 0, 0);
        acc11 = __builtin_amdgcn_mfma_f32_16x16x32_bf16(a1, b1, acc11, 0, 0, 0);
    }

    #pragma unroll
    for (int mi = 0; mi < 2; ++mi) {
        #pragma unroll
        for (int ni = 0; ni < 2; ++ni) {
            floatx4 acc = mi == 0 ? (ni == 0 ? acc00 : acc01) : (ni == 0 ? acc10 : acc11);
            int n = n0 + ni * 16 + m_l;
            #pragma unroll
            for (int r = 0; r < 4; ++r) {
                int row = m0 + mi * 16 + q4 * 4 + r;
                unsigned short v = f2bf(acc[r]);
                if (n < 256)      qb[(size_t)row * 256 + n] = v;
                else if (n < 512) kb[(size_t)row * 256 + (n - 256)] = v;
                else              vb[(size_t)row * 1024 + (n - 512)] = v;
            }
        }
    }
}

// ---------------------------------------------------------------------------
// Kernel 2: per (head, chunk) KV partials, TRANSPOSED output:
// kvp[h][c][dd][D], dd in [0,65) (64 = ones/den row), D contiguous (288 pad,
// pad never written). Row-contiguous writes per thread.
// ---------------------------------------------------------------------------
__global__ __launch_bounds__(320) void chunk_kv(
    const unsigned short* __restrict__ kb, const unsigned short* __restrict__ vb,
    float* __restrict__ kvp) {
    int h = blockIdx.x & 15, c = blockIdx.x >> 4;
    int l0 = c * CHUNK;
    __shared__ __align__(16) float ks[64][16];
    __shared__ __align__(16) float vs[64][64];
    int t = threadIdx.x;
    if (t < 256) {
        int m = t >> 2, i4 = (t & 3) * 4;
        ushort4 a = *(const ushort4*)&kb[(size_t)(l0 + m) * 256 + h * 16 + i4];
        ks[m][i4] = bf2f(a.x); ks[m][i4 + 1] = bf2f(a.y);
        ks[m][i4 + 2] = bf2f(a.z); ks[m][i4 + 3] = bf2f(a.w);
        int d16 = (t & 3) * 16;
        #pragma unroll
        for (int u = 0; u < 4; ++u) {
            ushort4 b = *(const ushort4*)&vb[(size_t)(l0 + m) * 1024 + h * 64 + d16 + u * 4];
            vs[m][d16 + u * 4]     = bf2f(b.x);
            vs[m][d16 + u * 4 + 1] = bf2f(b.y);
            vs[m][d16 + u * 4 + 2] = bf2f(b.z);
            vs[m][d16 + u * 4 + 3] = bf2f(b.w);
        }
    }
    __syncthreads();

    size_t base = (size_t)(h * NCHUNK + c) * 65 * DPAD;
    if (t < 256) {
        int d = t & 63, g = t >> 6;
        float accq[4][16] = {};
        float accl[4] = {};
        float accc = 0.f;
        for (int tt = 0; tt < 64; ++tt) {
            float w = vs[tt][d];
            float4 ki = *(const float4*)&ks[tt][g * 4];
            float kj[16];
            #pragma unroll
            for (int u = 0; u < 4; ++u) {
                float4 kk4 = *(const float4*)&ks[tt][u * 4];
                kj[u * 4 + 0] = kk4.x; kj[u * 4 + 1] = kk4.y; kj[u * 4 + 2] = kk4.z; kj[u * 4 + 3] = kk4.w;
            }
            float p0 = ki.x * w, p1 = ki.y * w, p2 = ki.z * w, p3 = ki.w * w;
            #pragma unroll
            for (int j = 0; j < 16; ++j) {
                accq[0][j] += p0 * kj[j];
                accq[1][j] += p1 * kj[j];
                accq[2][j] += p2 * kj[j];
                accq[3][j] += p3 * kj[j];
            }
            accl[0] += p0; accl[1] += p1; accl[2] += p2; accl[3] += p3;
            if (g == 0) accc += w;
        }
        float* rowp = kvp + base + (size_t)d * DPAD;
        #pragma unroll
        for (int a = 0; a < 4; ++a) {
            int iq = g * 4 + a;
            #pragma unroll
            for (int j = 0; j < 16; ++j) rowp[17 + iq * 16 + j] = accq[a][j] * C2F;
            rowp[1 + iq] = accl[a] * 0.5f;
        }
        if (g == 0) rowp[0] = accc;
    } else {
        int lane = t - 256;
        float* rowp = kvp + base + (size_t)64 * DPAD;
        for (int D = lane; D < DFEAT; D += 64) {
            float s = 0.f;
            if (D == 0) {
                s = 64.f;
            } else if (D < 17) {
                int i = D - 1;
                for (int tt = 0; tt < 64; ++tt) s += ks[tt][i];
                s *= 0.5f;
            } else {
                int e = D - 17, i = e >> 4, j = e & 15;
                for (int tt = 0; tt < 64; ++tt) s += ks[tt][i] * ks[tt][j];
                s *= C2F;
            }
            rowp[D] = s;
        }
    }
}

// ---------------------------------------------------------------------------
// Kernel 3: fp32 exclusive scan over 16 chunks -> bf16 kvt[h][c][80][288].
// Thread per (h, dd, D); consecutive threads = consecutive D (coalesced).
// 16*65*288 = 299520 threads = 1170 blocks x 256.
// ---------------------------------------------------------------------------
__global__ __launch_bounds__(256) void scan_kv(
    const float* __restrict__ kvp, unsigned short* __restrict__ kvt) {
    int idx = blockIdx.x * 256 + threadIdx.x;
    const int per_h = 65 * DPAD;
    if (idx >= NHEADS * per_h) return;
    int h = idx / per_h;
    int r = idx % per_h;
    int dd = r / DPAD, D = r % DPAD;
    size_t po = (size_t)(h * NCHUNK) * 65 * DPAD + (size_t)dd * DPAD + D;
    size_t to = (size_t)(h * NCHUNK) * 80 * DPAD + (size_t)dd * DPAD + D;
    const size_t pcs = (size_t)65 * DPAD;
    const size_t tcs = (size_t)80 * DPAD;
    if (D >= DFEAT) {   // pad region: deterministic zeros
        #pragma unroll
        for (int c = 0; c < NCHUNK; ++c) kvt[to + c * tcs] = 0;
        return;
    }
    float run = 0.f;
    #pragma unroll
    for (int c = 0; c < NCHUNK; ++c) {
        float v = kvp[po + c * pcs];
        kvt[to + c * tcs] = f2bf(run);
        run += v;
    }
}

// ---------------------------------------------------------------------------
// Kernel 4: attention via MFMA. Per (h,c) block, 4 waves, wave w owns rows
// l in [16w,16w+16).
//  cross: acc[nt] += qf(64x288 LDS bf16) x kvt tile (global, B-frag ready)
//  intra: S = QK^T (K=32, zero-padded) -> poly/causal -> P (LDS bf16)
//         acc[nt] += P x vT ; vT row 64 = ones => acc[4] = full denominator
// ---------------------------------------------------------------------------
#define QFP 296   // qf LDS row stride
__global__ __launch_bounds__(256) void attn(
    const unsigned short* __restrict__ qb, const unsigned short* __restrict__ kb,
    const unsigned short* __restrict__ vb, const unsigned short* __restrict__ kvt,
    unsigned short* __restrict__ ybB) {
    int h = blockIdx.x & 15, c = blockIdx.x >> 4;
    int l0 = c * CHUNK;
    __shared__ __align__(16) unsigned short qs[64][40];
    __shared__ __align__(16) unsigned short ksm[64][40];
    __shared__ __align__(16) unsigned short qf[64][QFP];
    __shared__ __align__(16) unsigned short vT[80][72];
    __shared__ __align__(16) unsigned short P[64][72];
    __shared__ float dens[64];
    int t = threadIdx.x, lane = t & 63, wave = t >> 6;
    int ml = lane & 15, q4 = lane >> 4;
    int m0 = wave * 16;

    // ---- stage q,k (zero-padded to K=32) and v^T (+ ones row 64)
    {
        int m = t >> 2, i4 = (t & 3) * 4;
        *(ushort4*)&qs[m][i4]  = *(const ushort4*)&qb[(size_t)(l0 + m) * 256 + h * 16 + i4];
        *(ushort4*)&ksm[m][i4] = *(const ushort4*)&kb[(size_t)(l0 + m) * 256 + h * 16 + i4];
        ushort4 z = {0, 0, 0, 0};
        *(ushort4*)&qs[m][16 + i4]  = z;
        *(ushort4*)&ksm[m][16 + i4] = z;
        int c0 = (t & 3) * 16;
        unsigned short tmp[16];
        #pragma unroll
        for (int u = 0; u < 4; ++u)
            *(ushort4*)&tmp[u * 4] = *(const ushort4*)&vb[(size_t)(l0 + m) * 1024 + h * 64 + c0 + u * 4];
        #pragma unroll
        for (int u = 0; u < 16; ++u) vT[c0 + u][m] = tmp[u];
    }
    if (t < 64) vT[64][t] = 0x3F80;   // 1.0 bf16
    __syncthreads();

    // ---- build qf[l][D] (bf16), zero-padded D in [273,296)
    {
        int l = t & 63, g = t >> 6;
        short8 v0 = *(const short8*)&qs[l][0];
        short8 v1 = *(const short8*)&qs[l][8];
        float qv[16];
        #pragma unroll
        for (int u = 0; u < 8; ++u) {
            qv[u]     = bf2f((unsigned short)v0[u]);
            qv[u + 8] = bf2f((unsigned short)v1[u]);
        }
        int lo = (g == 0) ? 0 : 69 + (g - 1) * 68;
        int hi = (g == 0) ? 69 : lo + 68;
        for (int D = lo; D < hi; ++D) {
            float val;
            if (D == 0) val = 1.f;
            else if (D < 17) val = qv[D - 1] * 0.5f;
            else { int e = D - 17; val = qv[e >> 4] * qv[e & 15] * C2F; }
            qf[l][D] = f2bf(val);
        }
        int zlo = 273 + g * 6, zhi = zlo + 6 > 296 ? 296 : zlo + 6;
        for (int D = zlo; D < zhi; ++D) qf[l][D] = 0;
    }
    __syncthreads();

    // ---- intra scores: S = QK^T, poly+causal -> P
    {
        short8 a = *(const short8*)&qs[m0 + ml][q4 * 8];
        #pragma unroll
        for (int ntt = 0; ntt < 4; ++ntt) {
            short8 b = *(const short8*)&ksm[ntt * 16 + ml][q4 * 8];
            floatx4 sres = {0.f, 0.f, 0.f, 0.f};
            sres = __builtin_amdgcn_mfma_f32_16x16x32_bf16(a, b, sres, 0, 0, 0);
            #pragma unroll
            for (int r = 0; r < 4; ++r) {
                int tt = ntt * 16 + ml;
                int lrow = m0 + q4 * 4 + r;
                float s = sres[r];
                float p = (tt <= lrow) ? (1.f + 0.25f * s + 0.03125f * s * s) : 0.f;
                P[lrow][tt] = f2bf(p);
            }
        }
    }

    // ---- cross term: qf x KV (B-frag straight from global kvt)
    const unsigned short* kvb = kvt + (size_t)(h * NCHUNK + c) * 80 * DPAD;
    floatx4 acc[5];
    #pragma unroll
    for (int i = 0; i < 5; ++i) acc[i] = (floatx4){0.f, 0.f, 0.f, 0.f};
    #pragma unroll 3
    for (int k0 = 0; k0 < DPAD; k0 += 32) {
        short8 a = *(const short8*)&qf[m0 + ml][k0 + q4 * 8];
        #pragma unroll
        for (int nt = 0; nt < 5; ++nt) {
            short8 b = *(const short8*)&kvb[(size_t)(nt * 16 + ml) * DPAD + k0 + q4 * 8];
            acc[nt] = __builtin_amdgcn_mfma_f32_16x16x32_bf16(a, b, acc[nt], 0, 0, 0);
        }
    }
    __syncthreads();   // P complete (all waves)

    // ---- intra PV (vT row 64 = ones completes the denominator in acc[4])
    #pragma unroll
    for (int k0 = 0; k0 < 64; k0 += 32) {
        short8 a = *(const short8*)&P[m0 + ml][k0 + q4 * 8];
        #pragma unroll
        for (int nt = 0; nt < 5; ++nt) {
            short8 b = *(const short8*)&vT[nt * 16 + ml][k0 + q4 * 8];
            acc[nt] = __builtin_amdgcn_mfma_f32_16x16x32_bf16(a, b, acc[nt], 0, 0, 0);
        }
    }
    if (ml == 0) {
        #pragma unroll
        for (int r = 0; r < 4; ++r) dens[m0 + q4 * 4 + r] = acc[4][r] + 1e-12f;
    }
    __syncthreads();

    // ---- epilogue: y = num/den -> bf16
    #pragma unroll
    for (int r = 0; r < 4; ++r) {
        int lrow = m0 + q4 * 4 + r;
        float dinv = 1.f / dens[lrow];
        unsigned short* yp = ybB + (size_t)(l0 + lrow) * 1024 + h * 64;
        #pragma unroll
        for (int nt = 0; nt < 4; ++nt)
            yp[nt * 16 + ml] = f2bf(acc[nt][r] * dinv);
    }
}

// ---------------------------------------------------------------------------
// Kernel 5: output projection via bf16 MFMA. out = y @ Wo^T (1024^3).
// ---------------------------------------------------------------------------
__global__ __launch_bounds__(256) void out_mfma(
    const unsigned short* __restrict__ A, const unsigned short* __restrict__ B,
    void* __restrict__ outv, const int* __restrict__ flagp) {
    int t = threadIdx.x;
    int wave = t >> 6, lane = t & 63;
    int m_l = lane & 15, q4 = lane >> 4;
    int m0 = blockIdx.y * 64 + (wave >> 1) * 32;
    int n0 = blockIdx.x * 64 + (wave & 1) * 32;

    const unsigned short* a0p = A + (size_t)(m0 + m_l) * DMODEL + q4 * 8;
    const unsigned short* a1p = a0p + 16 * DMODEL;
    const unsigned short* b0p = B + (size_t)(n0 + m_l) * DMODEL + q4 * 8;
    const unsigned short* b1p = b0p + 16 * DMODEL;

    floatx4 acc00 = {0.f,0.f,0.f,0.f}, acc01 = acc00, acc10 = acc00, acc11 = acc00;
    #pragma unroll 4
    for (int k0 = 0; k0 < DMODEL; k0 += 32) {
        short8 a0 = *(const short8*)(a0p + k0);
        short8 a1 = *(const short8*)(a1p + k0);
        short8 b0 = *(const short8*)(b0p + k0);
        short8 b1 = *(const short8*)(b1p + k0);
        acc00 = __builtin_amdgcn_mfma_f32_16x16x32_bf16(a0, b0, acc00, 0, 0, 0);
        acc01 = __builtin_amdgcn_mfma_f32_16x16x32_bf16(a0, b1, acc01, 0, 0, 0);
        acc10 = __builtin_amdgcn_mfma_f32_16x16x32_bf16(a1, b0, acc10, 0, 0, 0);
        acc11 = __builtin_amdgcn_mfma_f32_16x16x32_bf16(a1, b1, acc11, 0, 0, 0);
    }
    int fp32 = *flagp;
    #pragma unroll
    for (int mi = 0; mi < 2; ++mi) {
        #pragma unroll
        for (int ni = 0; ni < 2; ++ni) {
            floatx4 acc = mi == 0 ? (ni == 0 ? acc00 : acc01) : (ni == 0 ? acc10 : acc11);
            int n = n0 + ni * 16 + m_l;
            #pragma unroll
            for (int r = 0; r < 4; ++r) {
                int row = m0 + mi * 16 + q4 * 4 + r;
                size_t idx = (size_t)row * 1024 + n;
                if (fp32) ((float*)outv)[idx] = acc[r];
                else      ((unsigned short*)outv)[idx] = f2bf(acc[r]);
            }
        }
    }
}

// ---------------------------------------------------------------------------
extern "C" void kernel_launch(void* const* d_in, const int* in_sizes, int n_in,
                              void* d_out, int out_size, void* d_ws, size_t ws_size,
                              hipStream_t stream) {
    unsigned short* us = (unsigned short*)d_ws;
    float* ws = (float*)d_ws;
    unsigned short* hidB  = us + U_HID;
    unsigned short* wqkvB = us + U_WQKV;
    unsigned short* woB   = us + U_WO;
    unsigned short* ybB   = us + U_YB;
    unsigned short* qbB   = us + U_QB;
    unsigned short* kbB   = us + U_KB;
    unsigned short* vbB   = us + U_VB;
    unsigned short* kvtB  = us + U_KVT;
    float* kvp = ws + F_KVP;
    int*  flag = (int*)(ws + F_FLAG);
    size_t need = (size_t)(F_FLAG + 1) * 4ull;
    if (ws_size < need) return;

    detect_dtype<<<dim3(1), 256, 0, stream>>>((const unsigned short*)d_in[1], flag);
    convert_bf16<<<dim3(1792), 256, 0, stream>>>(d_in[0], d_in[1], d_in[2], d_in[3], d_in[4], us, flag);
    qkv_mfma<<<dim3(24, 16), 256, 0, stream>>>(hidB, wqkvB, qbB, kbB, vbB);
    chunk_kv<<<dim3(256), 320, 0, stream>>>(kbB, vbB, kvp);
    scan_kv<<<dim3(1170), 256, 0, stream>>>(kvp, kvtB);
    attn<<<dim3(256), 256, 0, stream>>>(qbB, kbB, vbB, kvtB, ybB);
    out_mfma<<<dim3(16, 16), 256, 0, stream>>>(ybB, woB, d_out, flag);
}

// Round 5
// 179.893 us; speedup vs baseline: 1.6077x; 1.0162x over previous
//
#include <hip/hip_runtime.h>

// Problem constants
#define LSEQ 1024
#define DMODEL 1024
#define NHEADS 16
#define FDIM 16
#define HDIM 64
#define DFEAT 273          // 1 + 16 + 256
#define CHUNK 64
#define NCHUNK 16
#define KPD 288            // kvp (fp32 partials) row stride
#define KVTP 296           // kvt (bf16 scanned state) row stride; 592B -> 2-way LDS banks
#define C2F 0.17677669529663687f   // 1/(4*sqrt(2))

typedef __attribute__((ext_vector_type(8))) short short8;   // 8 bf16 (4 VGPRs)
typedef __attribute__((ext_vector_type(4))) float floatx4;  // MFMA acc

__device__ __forceinline__ float bf2f(unsigned short u) {
    unsigned int x = ((unsigned int)u) << 16;
    return __builtin_bit_cast(float, x);
}
__device__ __forceinline__ unsigned short f2bf(float f) {
    unsigned int x = __builtin_bit_cast(unsigned int, f);
    unsigned int r = (x + 0x7fffu + ((x >> 16) & 1u)) >> 16;
    return (unsigned short)r;
}

// Per-block dtype detector: samples 1024 ushorts of Wq. bf16 data -> exponents
// cluster ~[100,135] (bad ~0%); fp32-as-ushort -> mantissa halves have uniform
// exponents (bad ~38%). Threshold 128/1024. Returns 1 if inputs are fp32.
__device__ __forceinline__ int block_detect_fp32(const unsigned short* wq) {
    __shared__ int cnt;
    if (threadIdx.x == 0) cnt = 0;
    __syncthreads();
    int bad = 0;
    for (int i = threadIdx.x; i < 1024; i += blockDim.x) {
        int e = (wq[i] >> 7) & 0xFF;
        if (e >= 143 || (e > 0 && e <= 80)) bad++;
    }
    if (bad) atomicAdd(&cnt, bad);
    __syncthreads();
    return cnt > 128;
}

// async global->LDS 16B per lane (wave-uniform LDS base + lane*16)
__device__ __forceinline__ void async_copy16(const void* g, void* l) {
    __builtin_amdgcn_global_load_lds(
        (const __attribute__((address_space(1))) unsigned int*)g,
        (__attribute__((address_space(3))) unsigned int*)l, 16, 0, 0);
}

// Workspace layout (ushort indices unless noted):
//   hidB  @0         (1048576)
//   wqkvB @1048576   (1572864)  rows 0..255 Wq, 256..511 Wk, 512..1535 Wv
//   woB   @2621440   (1048576)
//   ybB   @3670016   (1048576)
//   qbB   @4718592   (262144)   bf16 q  [1024][256]
//   kbB   @4980736   (262144)   bf16 k  [1024][256]
//   vbB   @5242880   (1048576)  bf16 v  [1024][1024]
//   kvtB  @6291456   (6062080)  bf16 KV exclusive prefix [h][c][80][296]
// float region F0 = 6176768 (float idx):
//   kvp  @F0         (4792320)  fp32 KV chunk partials [h][c][65][288]
#define U_HID  0
#define U_WQKV 1048576
#define U_WO   2621440
#define U_YB   3670016
#define U_QB   4718592
#define U_KB   4980736
#define U_VB   5242880
#define U_KVT  6291456
#define F0     6176768
#define F_KVP  F0
#define NCONVB 3670016

// ---------------------------------------------------------------------------
// Kernel 0: materialize all five inputs as packed bf16 in ws (dtype-proof).
// ---------------------------------------------------------------------------
__global__ __launch_bounds__(256) void convert_bf16(
    const void* __restrict__ s0, const void* __restrict__ s1,
    const void* __restrict__ s2, const void* __restrict__ s3,
    const void* __restrict__ s4, unsigned short* __restrict__ dst) {
    int fp32 = block_detect_fp32((const unsigned short*)s1);
    size_t e = ((size_t)blockIdx.x * 256 + threadIdx.x) * 8;
    if (e >= NCONVB) return;
    const void* src; size_t off;
    if (e < 1048576)      { src = s0; off = e; }
    else if (e < 1310720) { src = s1; off = e - 1048576; }
    else if (e < 1572864) { src = s2; off = e - 1310720; }
    else if (e < 2621440) { src = s3; off = e - 1572864; }
    else                  { src = s4; off = e - 2621440; }
    if (fp32) {
        const float* f = (const float*)src + off;
        float4 v0 = *(const float4*)f;
        float4 v1 = *(const float4*)(f + 4);
        ushort4 o0, o1;
        o0.x = f2bf(v0.x); o0.y = f2bf(v0.y); o0.z = f2bf(v0.z); o0.w = f2bf(v0.w);
        o1.x = f2bf(v1.x); o1.y = f2bf(v1.y); o1.z = f2bf(v1.z); o1.w = f2bf(v1.w);
        *(ushort4*)(dst + e) = o0;
        *(ushort4*)(dst + e + 4) = o1;
    } else {
        const unsigned short* u = (const unsigned short*)src + off;
        *(ushort4*)(dst + e) = *(const ushort4*)u;
        *(ushort4*)(dst + e + 4) = *(const ushort4*)(u + 4);
    }
}

// ---------------------------------------------------------------------------
// Kernel 1: QKV projection via bf16 MFMA; outputs bf16 q/k/v.
// ---------------------------------------------------------------------------
__global__ __launch_bounds__(256) void qkv_mfma(
    const unsigned short* __restrict__ A, const unsigned short* __restrict__ B,
    unsigned short* __restrict__ qb, unsigned short* __restrict__ kb,
    unsigned short* __restrict__ vb) {
    int t = threadIdx.x;
    int wave = t >> 6, lane = t & 63;
    int m_l = lane & 15, q4 = lane >> 4;
    int m0 = blockIdx.y * 64 + (wave >> 1) * 32;
    int n0 = blockIdx.x * 64 + (wave & 1) * 32;

    const unsigned short* a0p = A + (size_t)(m0 + m_l) * DMODEL + q4 * 8;
    const unsigned short* a1p = a0p + 16 * DMODEL;
    const unsigned short* b0p = B + (size_t)(n0 + m_l) * DMODEL + q4 * 8;
    const unsigned short* b1p = b0p + 16 * DMODEL;

    floatx4 acc00 = {0.f,0.f,0.f,0.f}, acc01 = acc00, acc10 = acc00, acc11 = acc00;
    #pragma unroll 4
    for (int k0 = 0; k0 < DMODEL; k0 += 32) {
        short8 a0 = *(const short8*)(a0p + k0);
        short8 a1 = *(const short8*)(a1p + k0);
        short8 b0 = *(const short8*)(b0p + k0);
        short8 b1 = *(const short8*)(b1p + k0);
        acc00 = __builtin_amdgcn_mfma_f32_16x16x32_bf16(a0, b0, acc00, 0, 0, 0);
        acc01 = __builtin_amdgcn_mfma_f32_16x16x32_bf16(a0, b1, acc01, 0, 0, 0);
        acc10 = __builtin_amdgcn_mfma_f32_16x16x32_bf16(a1, b0, acc10, 0, 0, 0);
        acc11 = __builtin_amdgcn_mfma_f32_16x16x32_bf16(a1, b1, acc11, 0, 0, 0);
    }

    #pragma unroll
    for (int mi = 0; mi < 2; ++mi) {
        #pragma unroll
        for (int ni = 0; ni < 2; ++ni) {
            floatx4 acc = mi == 0 ? (ni == 0 ? acc00 : acc01) : (ni == 0 ? acc10 : acc11);
            int n = n0 + ni * 16 + m_l;
            #pragma unroll
            for (int r = 0; r < 4; ++r) {
                int row = m0 + mi * 16 + q4 * 4 + r;
                unsigned short v = f2bf(acc[r]);
                if (n < 256)      qb[(size_t)row * 256 + n] = v;
                else if (n < 512) kb[(size_t)row * 256 + (n - 256)] = v;
                else              vb[(size_t)row * 1024 + (n - 512)] = v;
            }
        }
    }
}

// ---------------------------------------------------------------------------
// Kernel 2: per (head, chunk) KV partials, TRANSPOSED: kvp[h][c][dd][D],
// dd in [0,65) (64 = ones/den row), D-contiguous rows (stride 288).
// ---------------------------------------------------------------------------
__global__ __launch_bounds__(320) void chunk_kv(
    const unsigned short* __restrict__ kb, const unsigned short* __restrict__ vb,
    float* __restrict__ kvp) {
    int h = blockIdx.x & 15, c = blockIdx.x >> 4;
    int l0 = c * CHUNK;
    __shared__ __align__(16) float ks[64][16];
    __shared__ __align__(16) float vs[64][64];
    int t = threadIdx.x;
    if (t < 256) {
        int m = t >> 2, i4 = (t & 3) * 4;
        ushort4 a = *(const ushort4*)&kb[(size_t)(l0 + m) * 256 + h * 16 + i4];
        ks[m][i4] = bf2f(a.x); ks[m][i4 + 1] = bf2f(a.y);
        ks[m][i4 + 2] = bf2f(a.z); ks[m][i4 + 3] = bf2f(a.w);
        int d16 = (t & 3) * 16;
        #pragma unroll
        for (int u = 0; u < 4; ++u) {
            ushort4 b = *(const ushort4*)&vb[(size_t)(l0 + m) * 1024 + h * 64 + d16 + u * 4];
            vs[m][d16 + u * 4]     = bf2f(b.x);
            vs[m][d16 + u * 4 + 1] = bf2f(b.y);
            vs[m][d16 + u * 4 + 2] = bf2f(b.z);
            vs[m][d16 + u * 4 + 3] = bf2f(b.w);
        }
    }
    __syncthreads();

    size_t base = (size_t)(h * NCHUNK + c) * 65 * KPD;
    if (t < 256) {
        int d = t & 63, g = t >> 6;
        float accq[4][16] = {};
        float accl[4] = {};
        float accc = 0.f;
        for (int tt = 0; tt < 64; ++tt) {
            float w = vs[tt][d];
            float4 ki = *(const float4*)&ks[tt][g * 4];
            float kj[16];
            #pragma unroll
            for (int u = 0; u < 4; ++u) {
                float4 kk4 = *(const float4*)&ks[tt][u * 4];
                kj[u * 4 + 0] = kk4.x; kj[u * 4 + 1] = kk4.y; kj[u * 4 + 2] = kk4.z; kj[u * 4 + 3] = kk4.w;
            }
            float p0 = ki.x * w, p1 = ki.y * w, p2 = ki.z * w, p3 = ki.w * w;
            #pragma unroll
            for (int j = 0; j < 16; ++j) {
                accq[0][j] += p0 * kj[j];
                accq[1][j] += p1 * kj[j];
                accq[2][j] += p2 * kj[j];
                accq[3][j] += p3 * kj[j];
            }
            accl[0] += p0; accl[1] += p1; accl[2] += p2; accl[3] += p3;
            if (g == 0) accc += w;
        }
        float* rowp = kvp + base + (size_t)d * KPD;
        #pragma unroll
        for (int a = 0; a < 4; ++a) {
            int iq = g * 4 + a;
            #pragma unroll
            for (int j = 0; j < 16; ++j) rowp[17 + iq * 16 + j] = accq[a][j] * C2F;
            rowp[1 + iq] = accl[a] * 0.5f;
        }
        if (g == 0) rowp[0] = accc;
    } else {
        int lane = t - 256;
        float* rowp = kvp + base + (size_t)64 * KPD;
        for (int D = lane; D < DFEAT; D += 64) {
            float s = 0.f;
            if (D == 0) {
                s = 64.f;
            } else if (D < 17) {
                int i = D - 1;
                for (int tt = 0; tt < 64; ++tt) s += ks[tt][i];
                s *= 0.5f;
            } else {
                int e = D - 17, i = e >> 4, j = e & 15;
                for (int tt = 0; tt < 64; ++tt) s += ks[tt][i] * ks[tt][j];
                s *= C2F;
            }
            rowp[D] = s;
        }
    }
}

// ---------------------------------------------------------------------------
// Kernel 3: fp32 exclusive scan over 16 chunks -> bf16 kvt[h][c][80][296].
// Thread per (h, dd, D), D < 296; D >= 273 emits zeros (pad).
// 16*65*296 = 307840 threads -> 1203 blocks x 256.
// ---------------------------------------------------------------------------
__global__ __launch_bounds__(256) void scan_kv(
    const float* __restrict__ kvp, unsigned short* __restrict__ kvt) {
    int idx = blockIdx.x * 256 + threadIdx.x;
    const int per_h = 65 * KVTP;
    if (idx >= NHEADS * per_h) return;
    int h = idx / per_h;
    int r = idx % per_h;
    int dd = r / KVTP, D = r % KVTP;
    size_t to = (size_t)(h * NCHUNK) * 80 * KVTP + (size_t)dd * KVTP + D;
    const size_t tcs = (size_t)80 * KVTP;
    if (D >= DFEAT) {   // pad region: deterministic zeros
        #pragma unroll
        for (int c = 0; c < NCHUNK; ++c) kvt[to + c * tcs] = 0;
        return;
    }
    size_t po = (size_t)(h * NCHUNK) * 65 * KPD + (size_t)dd * KPD + D;
    const size_t pcs = (size_t)65 * KPD;
    float run = 0.f;
    #pragma unroll
    for (int c = 0; c < NCHUNK; ++c) {
        float v = kvp[po + c * pcs];
        kvt[to + c * tcs] = f2bf(run);
        run += v;
    }
}

// ---------------------------------------------------------------------------
// Kernel 4: attention via MFMA. Per (h,c) block, 4 waves.
// kvt chunk (80x296 bf16 = 47360B) DMA'd to LDS ONCE via global_load_lds
// (issued first; overlaps q/k/v staging + qf build; drained by barrier).
//  cross: acc[nt] += qf (LDS A-frag) x kvS (LDS B-frag), K=288
//  intra: S = QK^T -> poly/causal -> P -> acc[nt] += P x vT (row 64 = ones
//         completes the denominator in acc[4] col 0)
// ---------------------------------------------------------------------------
#define QFP 296   // qf LDS row stride (592B -> 2-way banks, free)
__global__ __launch_bounds__(256) void attn(
    const unsigned short* __restrict__ qb, const unsigned short* __restrict__ kb,
    const unsigned short* __restrict__ vb, const unsigned short* __restrict__ kvt,
    unsigned short* __restrict__ ybB) {
    int h = blockIdx.x & 15, c = blockIdx.x >> 4;
    int l0 = c * CHUNK;
    __shared__ __align__(16) unsigned short kvS[80][KVTP];   // 47360B
    __shared__ __align__(16) unsigned short qs[64][40];
    __shared__ __align__(16) unsigned short ksm[64][40];
    __shared__ __align__(16) unsigned short qf[64][QFP];
    __shared__ __align__(16) unsigned short vT[80][72];
    __shared__ __align__(16) unsigned short P[64][72];
    __shared__ float dens[64];
    int t = threadIdx.x, lane = t & 63, wave = t >> 6;
    int ml = lane & 15, q4 = lane >> 4;
    int m0 = wave * 16;

    // ---- issue kvt -> LDS DMA first (47360B; 47 x 1KB wave-instructions;
    //      last one over-reads 768B into the adjacent ws region - benign)
    const unsigned short* kvb = kvt + (size_t)(h * NCHUNK + c) * 80 * KVTP;
    {
        const char* g = (const char*)kvb;
        char* l = (char*)&kvS[0][0];
        #pragma unroll
        for (int i = wave; i < 47; i += 4)
            async_copy16(g + i * 1024 + lane * 16, l + i * 1024 + lane * 16);
    }

    // ---- stage q,k (zero-padded to K=32) and v^T (+ ones row 64)
    {
        int m = t >> 2, i4 = (t & 3) * 4;
        *(ushort4*)&qs[m][i4]  = *(const ushort4*)&qb[(size_t)(l0 + m) * 256 + h * 16 + i4];
        *(ushort4*)&ksm[m][i4] = *(const ushort4*)&kb[(size_t)(l0 + m) * 256 + h * 16 + i4];
        ushort4 z = {0, 0, 0, 0};
        *(ushort4*)&qs[m][16 + i4]  = z;
        *(ushort4*)&ksm[m][16 + i4] = z;
        int c0 = (t & 3) * 16;
        unsigned short tmp[16];
        #pragma unroll
        for (int u = 0; u < 4; ++u)
            *(ushort4*)&tmp[u * 4] = *(const ushort4*)&vb[(size_t)(l0 + m) * 1024 + h * 64 + c0 + u * 4];
        #pragma unroll
        for (int u = 0; u < 16; ++u) vT[c0 + u][m] = tmp[u];
    }
    if (t < 64) vT[64][t] = 0x3F80;   // 1.0 bf16
    __syncthreads();   // drains DMA (vmcnt) + staging

    // ---- build qf[l][D] (bf16), zero-padded D in [273,296)
    {
        int l = t & 63, g = t >> 6;
        short8 v0 = *(const short8*)&qs[l][0];
        short8 v1 = *(const short8*)&qs[l][8];
        float qv[16];
        #pragma unroll
        for (int u = 0; u < 8; ++u) {
            qv[u]     = bf2f((unsigned short)v0[u]);
            qv[u + 8] = bf2f((unsigned short)v1[u]);
        }
        int lo = (g == 0) ? 0 : 69 + (g - 1) * 68;
        int hi = (g == 0) ? 69 : lo + 68;
        for (int D = lo; D < hi; ++D) {
            float val;
            if (D == 0) val = 1.f;
            else if (D < 17) val = qv[D - 1] * 0.5f;
            else { int e = D - 17; val = qv[e >> 4] * qv[e & 15] * C2F; }
            qf[l][D] = f2bf(val);
        }
        int zlo = 273 + g * 6, zhi = zlo + 6 > 296 ? 296 : zlo + 6;
        for (int D = zlo; D < zhi; ++D) qf[l][D] = 0;
    }

    // ---- intra scores: S = QK^T, poly+causal -> P
    {
        short8 a = *(const short8*)&qs[m0 + ml][q4 * 8];
        #pragma unroll
        for (int ntt = 0; ntt < 4; ++ntt) {
            short8 b = *(const short8*)&ksm[ntt * 16 + ml][q4 * 8];
            floatx4 sres = {0.f, 0.f, 0.f, 0.f};
            sres = __builtin_amdgcn_mfma_f32_16x16x32_bf16(a, b, sres, 0, 0, 0);
            #pragma unroll
            for (int r = 0; r < 4; ++r) {
                int tt = ntt * 16 + ml;
                int lrow = m0 + q4 * 4 + r;
                float s = sres[r];
                float p = (tt <= lrow) ? (1.f + 0.25f * s + 0.03125f * s * s) : 0.f;
                P[lrow][tt] = f2bf(p);
            }
        }
    }
    __syncthreads();   // qf + P complete

    // ---- cross term: qf x KV, all from LDS
    floatx4 acc[5];
    #pragma unroll
    for (int i = 0; i < 5; ++i) acc[i] = (floatx4){0.f, 0.f, 0.f, 0.f};
    #pragma unroll
    for (int k0 = 0; k0 < 288; k0 += 32) {
        short8 a = *(const short8*)&qf[m0 + ml][k0 + q4 * 8];
        #pragma unroll
        for (int nt = 0; nt < 5; ++nt) {
            short8 b = *(const short8*)&kvS[nt * 16 + ml][k0 + q4 * 8];
            acc[nt] = __builtin_amdgcn_mfma_f32_16x16x32_bf16(a, b, acc[nt], 0, 0, 0);
        }
    }

    // ---- intra PV (vT row 64 = ones completes the denominator in acc[4])
    #pragma unroll
    for (int k0 = 0; k0 < 64; k0 += 32) {
        short8 a = *(const short8*)&P[m0 + ml][k0 + q4 * 8];
        #pragma unroll
        for (int nt = 0; nt < 5; ++nt) {
            short8 b = *(const short8*)&vT[nt * 16 + ml][k0 + q4 * 8];
            acc[nt] = __builtin_amdgcn_mfma_f32_16x16x32_bf16(a, b, acc[nt], 0, 0, 0);
        }
    }
    if (ml == 0) {
        #pragma unroll
        for (int r = 0; r < 4; ++r) dens[m0 + q4 * 4 + r] = acc[4][r] + 1e-12f;
    }
    __syncthreads();

    // ---- epilogue: y = num/den -> bf16
    #pragma unroll
    for (int r = 0; r < 4; ++r) {
        int lrow = m0 + q4 * 4 + r;
        float dinv = 1.f / dens[lrow];
        unsigned short* yp = ybB + (size_t)(l0 + lrow) * 1024 + h * 64;
        #pragma unroll
        for (int nt = 0; nt < 4; ++nt)
            yp[nt * 16 + ml] = f2bf(acc[nt][r] * dinv);
    }
}

// ---------------------------------------------------------------------------
// Kernel 5: output projection via bf16 MFMA. out = y @ Wo^T (1024^3).
// Output dtype chosen per-block by the inline detector.
// ---------------------------------------------------------------------------
__global__ __launch_bounds__(256) void out_mfma(
    const unsigned short* __restrict__ A, const unsigned short* __restrict__ B,
    void* __restrict__ outv, const unsigned short* __restrict__ wqraw) {
    int fp32 = block_detect_fp32(wqraw);
    int t = threadIdx.x;
    int wave = t >> 6, lane = t & 63;
    int m_l = lane & 15, q4 = lane >> 4;
    int m0 = blockIdx.y * 64 + (wave >> 1) * 32;
    int n0 = blockIdx.x * 64 + (wave & 1) * 32;

    const unsigned short* a0p = A + (size_t)(m0 + m_l) * DMODEL + q4 * 8;
    const unsigned short* a1p = a0p + 16 * DMODEL;
    const unsigned short* b0p = B + (size_t)(n0 + m_l) * DMODEL + q4 * 8;
    const unsigned short* b1p = b0p + 16 * DMODEL;

    floatx4 acc00 = {0.f,0.f,0.f,0.f}, acc01 = acc00, acc10 = acc00, acc11 = acc00;
    #pragma unroll 4
    for (int k0 = 0; k0 < DMODEL; k0 += 32) {
        short8 a0 = *(const short8*)(a0p + k0);
        short8 a1 = *(const short8*)(a1p + k0);
        short8 b0 = *(const short8*)(b0p + k0);
        short8 b1 = *(const short8*)(b1p + k0);
        acc00 = __builtin_amdgcn_mfma_f32_16x16x32_bf16(a0, b0, acc00, 0, 0, 0);
        acc01 = __builtin_amdgcn_mfma_f32_16x16x32_bf16(a0, b1, acc01, 0, 0, 0);
        acc10 = __builtin_amdgcn_mfma_f32_16x16x32_bf16(a1, b0, acc10, 0, 0, 0);
        acc11 = __builtin_amdgcn_mfma_f32_16x16x32_bf16(a1, b1, acc11, 0, 0, 0);
    }
    #pragma unroll
    for (int mi = 0; mi < 2; ++mi) {
        #pragma unroll
        for (int ni = 0; ni < 2; ++ni) {
            floatx4 acc = mi == 0 ? (ni == 0 ? acc00 : acc01) : (ni == 0 ? acc10 : acc11);
            int n = n0 + ni * 16 + m_l;
            #pragma unroll
            for (int r = 0; r < 4; ++r) {
                int row = m0 + mi * 16 + q4 * 4 + r;
                size_t idx = (size_t)row * 1024 + n;
                if (fp32) ((float*)outv)[idx] = acc[r];
                else      ((unsigned short*)outv)[idx] = f2bf(acc[r]);
            }
        }
    }
}

// ---------------------------------------------------------------------------
extern "C" void kernel_launch(void* const* d_in, const int* in_sizes, int n_in,
                              void* d_out, int out_size, void* d_ws, size_t ws_size,
                              hipStream_t stream) {
    unsigned short* us = (unsigned short*)d_ws;
    float* ws = (float*)d_ws;
    unsigned short* hidB  = us + U_HID;
    unsigned short* wqkvB = us + U_WQKV;
    unsigned short* woB   = us + U_WO;
    unsigned short* ybB   = us + U_YB;
    unsigned short* qbB   = us + U_QB;
    unsigned short* kbB   = us + U_KB;
    unsigned short* vbB   = us + U_VB;
    unsigned short* kvtB  = us + U_KVT;
    float* kvp = ws + F_KVP;
    size_t need = ((size_t)F_KVP + 4792320ull) * 4ull + 1024ull;  // +DMA slack
    if (ws_size < need) return;

    convert_bf16<<<dim3(1792), 256, 0, stream>>>(d_in[0], d_in[1], d_in[2], d_in[3], d_in[4], us);
    qkv_mfma<<<dim3(24, 16), 256, 0, stream>>>(hidB, wqkvB, qbB, kbB, vbB);
    chunk_kv<<<dim3(256), 320, 0, stream>>>(kbB, vbB, kvp);
    scan_kv<<<dim3(1203), 256, 0, stream>>>(kvp, kvtB);
    attn<<<dim3(256), 256, 0, stream>>>(qbB, kbB, vbB, kvtB, ybB);
    out_mfma<<<dim3(16, 16), 256, 0, stream>>>(ybB, woB, d_out, (const unsigned short*)d_in[1]);
}